// Round 3
// baseline (208.431 us; speedup 1.0000x reference)
//
#include <hip/hip_runtime.h>
#include <hip/hip_bf16.h>

constexpr int NB = 8;      // batch
constexpr int T  = 2048;   // seq
constexpr int C  = 1024;   // embed
constexpr int Hd = 128;    // head size

typedef short bf16x8 __attribute__((ext_vector_type(8)));
typedef float floatx4 __attribute__((ext_vector_type(4)));

__device__ __forceinline__ ushort f2bf(float x) {
    return __builtin_bit_cast(ushort, __float2bfloat16(x));
}
__device__ __forceinline__ float bf2f(ushort u) {
    unsigned int x = ((unsigned int)u) << 16;
    return __builtin_bit_cast(float, x);
}
__device__ __forceinline__ void async16(ushort* lds, const ushort* g) {
    __builtin_amdgcn_global_load_lds(
        (const __attribute__((address_space(1))) unsigned int*)g,
        (__attribute__((address_space(3))) unsigned int*)lds, 16, 0, 0);
}

// ---------------------------------------------------------------------------
// Kernel 1: fused fp32->bf16 convert for X and stacked W (Wq scaled). UNCHANGED.
// ---------------------------------------------------------------------------
__global__ __launch_bounds__(256) void convert_xw(
    const float* __restrict__ X, const float* __restrict__ Wq,
    const float* __restrict__ Wk, const float* __restrict__ Wv,
    ushort* __restrict__ Xb, ushort* __restrict__ Wb)
{
    int bid = blockIdx.x;
    if (bid < 8192) {
        size_t i = ((size_t)bid * 256 + threadIdx.x) * 8;
        float4 a = *(const float4*)&X[i];
        float4 b = *(const float4*)&X[i + 4];
        bf16x8 o;
        o[0] = (short)f2bf(a.x); o[1] = (short)f2bf(a.y);
        o[2] = (short)f2bf(a.z); o[3] = (short)f2bf(a.w);
        o[4] = (short)f2bf(b.x); o[5] = (short)f2bf(b.y);
        o[6] = (short)f2bf(b.z); o[7] = (short)f2bf(b.w);
        *(bf16x8*)&Xb[i] = o;
    } else {
        int g = (bid - 8192) * 256 + threadIdx.x;
        size_t base = (size_t)g * 8;
        int sel = (int)(base >> 17);
        const float* W = sel == 0 ? Wq : (sel == 1 ? Wk : Wv);
        float s = (sel == 0) ? 0.12751744f : 1.0f;     // log2e/sqrt(128) in Wq
        size_t off = base - (size_t)sel * 131072;
        float4 a = *(const float4*)&W[off];
        float4 b = *(const float4*)&W[off + 4];
        bf16x8 o;
        o[0] = (short)f2bf(a.x * s); o[1] = (short)f2bf(a.y * s);
        o[2] = (short)f2bf(a.z * s); o[3] = (short)f2bf(a.w * s);
        o[4] = (short)f2bf(b.x * s); o[5] = (short)f2bf(b.y * s);
        o[6] = (short)f2bf(b.z * s); o[7] = (short)f2bf(b.w * s);
        *(bf16x8*)&Wb[base] = o;
    }
}

// ---------------------------------------------------------------------------
// Kernel 2: QKV GEMM bf16, BM=128 BN=64 BK=64. UNCHANGED.
// ---------------------------------------------------------------------------
__global__ __launch_bounds__(256) void qkv_gemm(
    const ushort* __restrict__ Xb, const ushort* __restrict__ Wb,
    ushort* __restrict__ Qo, ushort* __restrict__ Ko, ushort* __restrict__ Vt)
{
    __shared__ ushort SM[12288];          // 24KB: Al(8192) + Bl(4096); TL overlays
    ushort* Al = SM;                      // 128x64
    ushort* Bl = SM + 8192;               // 64x64
    const int m0 = blockIdx.x * 128;
    const int n0 = blockIdx.y * 64;       // row into stacked Wb [384][1024]
    const int tid = threadIdx.x, lane = tid & 63, wave = tid >> 6;
    const int quad = lane >> 4, colL = lane & 15;
    const int wm = (wave & 1) * 64, wn = (wave >> 1) * 32;
    const int lr = lane >> 3;
    const int lcs = ((lane & 7) ^ (lr & 7)) * 8;   // swizzled source column

    floatx4 acc[4][2] = {};

    for (int k0 = 0; k0 < C; k0 += 64) {
        for (int t = 0; t < 4; ++t) {
            int q = wave * 4 + t;                   // 16 chunks (A: 128x64)
            async16(&Al[q * 512 + lane * 8],
                    &Xb[(size_t)(m0 + q * 8 + lr) * C + k0 + lcs]);
        }
        for (int t = 0; t < 2; ++t) {
            int q = wave * 2 + t;                   // 8 chunks (B: 64x64)
            async16(&Bl[q * 512 + lane * 8],
                    &Wb[(size_t)(n0 + q * 8 + lr) * C + k0 + lcs]);
        }
        __syncthreads();

        bf16x8 af[2][4], bfr[2][2];
        for (int kk = 0; kk < 2; ++kk) {
            for (int mt = 0; mt < 4; ++mt)
                af[kk][mt] = *(const bf16x8*)
                    &Al[(wm + mt * 16 + colL) * 64 + (((kk * 4 + quad) ^ (colL & 7))) * 8];
            for (int nt = 0; nt < 2; ++nt)
                bfr[kk][nt] = *(const bf16x8*)
                    &Bl[(wn + nt * 16 + colL) * 64 + (((kk * 4 + quad) ^ (colL & 7))) * 8];
        }
        for (int kk = 0; kk < 2; ++kk)
            for (int mt = 0; mt < 4; ++mt)
                for (int nt = 0; nt < 2; ++nt)
                    acc[mt][nt] = __builtin_amdgcn_mfma_f32_16x16x32_bf16(
                        af[kk][mt], bfr[kk][nt], acc[mt][nt], 0, 0, 0);
        __syncthreads();
    }

    const int sel = n0 >> 7;              // 0,0,1,1,2,2
    const int h0 = n0 & 127;              // 0 or 64
    if (sel < 2) {
        ushort* dst = sel == 0 ? Qo : Ko;
        for (int mt = 0; mt < 4; ++mt)
            for (int nt = 0; nt < 2; ++nt)
                for (int r = 0; r < 4; ++r) {
                    int row = m0 + wm + mt * 16 + quad * 4 + r;
                    int h = h0 + wn + nt * 16 + colL;
                    dst[(size_t)row * Hd + h] = f2bf(acc[mt][nt][r]);
                }
    } else {
        // V: transpose 128t x 64h tile through LDS scratch TL[128][66]
        ushort* TL = SM;                  // 8448 ushorts, overlays Al/Bl
        for (int mt = 0; mt < 4; ++mt)
            for (int nt = 0; nt < 2; ++nt)
                for (int r = 0; r < 4; ++r)
                    TL[(wm + mt * 16 + quad * 4 + r) * 66 + wn + nt * 16 + colL] =
                        f2bf(acc[mt][nt][r]);
        __syncthreads();
        const int b = m0 >> 11, tb = m0 & 2047;
        const int h = tid & 63, tq = tid >> 6;     // thread: h col, 32-t strip
        for (int st = 0; st < 4; ++st) {
            int t0 = tq * 32 + st * 8;
            bf16x8 o;
            for (int jx = 0; jx < 8; ++jx)
                o[jx] = (short)TL[(t0 + jx) * 66 + h];
            *(bf16x8*)&Vt[((size_t)b * Hd + h0 + h) * T + tb + t0] = o;
        }
    }
}

// ---------------------------------------------------------------------------
// Kernel 3 (R3): 256-key chunk, SINGLE softmax, no online merge.
// 256 threads / 4 waves / 32 q-rows per wave  -> R0's proven register
// envelope: __launch_bounds__(256,2) caps VGPR at 256 (R1/R2 spilled at
// cap-128 despite ~100 live values; R0 never spilled at cap-256).
// Block = (b, j qtile of 128 rows, c pair of 128-key subchunks {2c,2c+1}).
// accS[2][16] (128 VGPR) holds all 256 scores; K staged in two 32KB passes
// over region A; after softmax A becomes P (per-wave private); V staged in
// two 32KB passes over region Bv; PV accumulates both halves, same max ->
// NO rescale. LDS 64KB total -> 2 blocks/CU (same as R0).
// ---------------------------------------------------------------------------
__global__ __launch_bounds__(256, 2) void attn_partial(
    const ushort* __restrict__ Q, const ushort* __restrict__ Kg,
    const ushort* __restrict__ Vt, ushort* __restrict__ Opart,
    float* __restrict__ mpart, float* __restrict__ lpart)
{
    __shared__ ushort A[128 * 128];    // 32KB: K subchunk, then P [4w][32r][128c]
    __shared__ ushort Bv[128 * 128];   // 32KB: V subchunk [h][key] swizzled

    const int tid = threadIdx.x, lane = tid & 63, wave = tid >> 6;
    const int quad = lane >> 4, colL = lane & 15;

    int id = blockIdx.x;               // 0..575; batch-interleaved heavy-first
    int b = id & 7;
    int rem = id >> 3;                 // 0..71 within batch, j descending
    int j = 15;
    while (rem >= (j >> 1) + 1) { rem -= (j >> 1) + 1; --j; }
    const int c = rem;                 // pair index: subchunks 2c, 2c+1
    const int q0 = j * 128;
    const int nsub = (2 * c + 1 <= j) ? 2 : 1;
    const int r16 = tid >> 4, p16 = tid & 15;

    // ---- stage K subchunk 0 + Q fragments ----
    {
        const int k0 = 2 * c * 128;
        for (int t = 0; t < 8; ++t) {
            int row = t * 16 + r16;
            async16(&A[t * 2048 + tid * 8],
                    &Kg[((size_t)b * T + k0 + row) * Hd + ((p16 ^ (row & 15)) * 8)]);
        }
    }
    bf16x8 qa[2][4];
    for (int mi = 0; mi < 2; ++mi) {
        const ushort* qp =
            &Q[((size_t)b * T + q0 + wave * 32 + mi * 16 + colL) * Hd + quad * 8];
        for (int ks = 0; ks < 4; ++ks)
            qa[mi][ks] = *(const bf16x8*)&qp[ks * 32];
    }
    __syncthreads();                   // [S1] K0 visible

    floatx4 accS[2][16] = {};
    // QK^T half 0
    for (int ks = 0; ks < 4; ++ks)
        for (int nt = 0; nt < 8; ++nt) {
            int krow = nt * 16 + colL;
            bf16x8 kb = *(const bf16x8*)&A[krow * 128 + (((ks * 4 + quad) ^ colL) * 8)];
            accS[0][nt] = __builtin_amdgcn_mfma_f32_16x16x32_bf16(qa[0][ks], kb, accS[0][nt], 0, 0, 0);
            accS[1][nt] = __builtin_amdgcn_mfma_f32_16x16x32_bf16(qa[1][ks], kb, accS[1][nt], 0, 0, 0);
        }

    if (nsub == 2) {
        __syncthreads();               // [S2] K0 reads done
        const int k0 = (2 * c + 1) * 128;
        for (int t = 0; t < 8; ++t) {
            int row = t * 16 + r16;
            async16(&A[t * 2048 + tid * 8],
                    &Kg[((size_t)b * T + k0 + row) * Hd + ((p16 ^ (row & 15)) * 8)]);
        }
        __syncthreads();               // [S3] K1 visible
        for (int ks = 0; ks < 4; ++ks)
            for (int nt = 0; nt < 8; ++nt) {
                int krow = nt * 16 + colL;
                bf16x8 kb = *(const bf16x8*)&A[krow * 128 + (((ks * 4 + quad) ^ colL) * 8)];
                accS[0][8 + nt] = __builtin_amdgcn_mfma_f32_16x16x32_bf16(qa[0][ks], kb, accS[0][8 + nt], 0, 0, 0);
                accS[1][8 + nt] = __builtin_amdgcn_mfma_f32_16x16x32_bf16(qa[1][ks], kb, accS[1][8 + nt], 0, 0, 0);
            }
    }

    // causal mask: only the last subchunk (2c+nsub-1) can be diagonal
    if (2 * c + nsub - 1 == j) {
        const int base = (nsub - 1) * 8;
        for (int mi = 0; mi < 2; ++mi)
            for (int nt = 0; nt < 8; ++nt)
                for (int rr = 0; rr < 4; ++rr) {
                    int lrow = wave * 32 + mi * 16 + quad * 4 + rr;
                    int lcol = nt * 16 + colL;
                    if (lcol > lrow) accS[mi][base + nt][rr] = -__builtin_inff();
                }
    }

    // single softmax max over all staged columns
    float m_r[2][4], l_r[2][4];
    for (int mi = 0; mi < 2; ++mi)
        for (int rr = 0; rr < 4; ++rr) {
            float mx = accS[mi][0][rr];
            for (int nt = 1; nt < 8; ++nt) mx = fmaxf(mx, accS[mi][nt][rr]);
            if (nsub == 2)
                for (int nt = 8; nt < 16; ++nt) mx = fmaxf(mx, accS[mi][nt][rr]);
            for (int off = 1; off < 16; off <<= 1)
                mx = fmaxf(mx, __shfl_xor(mx, off, 64));
            m_r[mi][rr] = mx;
            l_r[mi][rr] = 0.f;
        }

    __syncthreads();                   // [S4] all K reads done -> A becomes P

    floatx4 Oacc[2][8] = {};
    ushort* Pw = &A[wave * 4096];      // [32 rows][128 keys], col^((row&7)<<4)

    for (int half = 0; half < 2; ++half) {
        if (half == 1 && nsub == 1) break;
        const int base = half * 8;

        // exp + P write for this half; accumulate l
        for (int mi = 0; mi < 2; ++mi) {
            float ls[4] = {0.f, 0.f, 0.f, 0.f};
            for (int nt = 0; nt < 8; ++nt)
                for (int rr = 0; rr < 4; ++rr) {
                    float p = __builtin_amdgcn_exp2f(accS[mi][base + nt][rr] - m_r[mi][rr]);
                    ls[rr] += p;
                    int prow = mi * 16 + quad * 4 + rr;
                    Pw[prow * 128 + ((nt * 16 + colL) ^ ((prow & 7) << 4))] = f2bf(p);
                }
            for (int rr = 0; rr < 4; ++rr) {
                float s = ls[rr];
                for (int off = 1; off < 16; off <<= 1)
                    s += __shfl_xor(s, off, 64);
                l_r[mi][rr] += s;
            }
        }

        // stage V for this half
        {
            const int k0 = (2 * c + half) * 128;
            for (int t = 0; t < 8; ++t) {
                int hrow = t * 16 + r16;
                async16(&Bv[t * 2048 + tid * 8],
                        &Vt[((size_t)b * Hd + hrow) * T + k0 + ((p16 ^ (hrow & 15)) * 8)]);
            }
        }
        __syncthreads();               // [S5/S7] V visible (drains lgkm for P too)

        bf16x8 pa[2][4];
        for (int mi = 0; mi < 2; ++mi) {
            int prow = mi * 16 + colL;
            int sw = (prow & 7) << 4;
            for (int ks = 0; ks < 4; ++ks)
                pa[mi][ks] = *(const bf16x8*)&Pw[prow * 128 + ((ks * 32 + quad * 8) ^ sw)];
        }
        for (int ks = 0; ks < 4; ++ks)
            for (int th = 0; th < 8; ++th) {
                int hrow = th * 16 + colL;
                bf16x8 vb = *(const bf16x8*)&Bv[hrow * 128 + (((ks * 4 + quad) ^ colL) * 8)];
                Oacc[0][th] = __builtin_amdgcn_mfma_f32_16x16x32_bf16(pa[0][ks], vb, Oacc[0][th], 0, 0, 0);
                Oacc[1][th] = __builtin_amdgcn_mfma_f32_16x16x32_bf16(pa[1][ks], vb, Oacc[1][th], 0, 0, 0);
            }
        if (half == 0 && nsub == 2)
            __syncthreads();           // [S6] V0 reads done before V1 staging
    }

    // slot = b*72 + prefix(j) + c, prefix(j) = hj^2 + hj + (j&1)*(hj+1)
    const int hj = j >> 1;
    const int slot = b * 72 + hj * hj + hj + (j & 1) * (hj + 1) + c;
    ushort* Op = &Opart[(size_t)slot * 16384];
    for (int mi = 0; mi < 2; ++mi)
        for (int th = 0; th < 8; ++th)
            for (int rr = 0; rr < 4; ++rr) {
                int row = wave * 32 + mi * 16 + quad * 4 + rr;
                Op[row * 128 + th * 16 + colL] = f2bf(Oacc[mi][th][rr]);
            }
    if (colL == 0)
        for (int mi = 0; mi < 2; ++mi)
            for (int rr = 0; rr < 4; ++rr) {
                int row = wave * 32 + mi * 16 + quad * 4 + rr;
                mpart[(size_t)slot * 128 + row] = m_r[mi][rr];
                lpart[(size_t)slot * 128 + row] = l_r[mi][rr];
            }
}

// ---------------------------------------------------------------------------
// Kernel 4: merge partials (<=8 per row), write fp32 out. Same as R2.
// ---------------------------------------------------------------------------
__global__ __launch_bounds__(256) void attn_combine(
    const ushort* __restrict__ Opart, const float* __restrict__ mpart,
    const float* __restrict__ lpart, float* __restrict__ out)
{
    const int j = blockIdx.x, b = blockIdx.y;
    const int nch = (j >> 1) + 1;
    const int hj = j >> 1;
    const int sbase = b * 72 + hj * hj + hj + (j & 1) * (hj + 1);
    const int t = threadIdx.x;
    const int row = blockIdx.z * 32 + (t >> 3);
    const int h0 = (t & 7) * 16;

    float mv[8], lv[8], wgt[8];
    float M = -__builtin_inff();
#pragma unroll
    for (int cc = 0; cc < 8; ++cc) {
        if (cc < nch) {
            mv[cc] = mpart[(size_t)(sbase + cc) * 128 + row];
            lv[cc] = lpart[(size_t)(sbase + cc) * 128 + row];
            M = fmaxf(M, mv[cc]);
        }
    }
    float ltot = 0.f;
#pragma unroll
    for (int cc = 0; cc < 8; ++cc) {
        if (cc < nch) {
            wgt[cc] = __builtin_amdgcn_exp2f(mv[cc] - M);
            ltot += lv[cc] * wgt[cc];
        }
    }

    float o[16];
#pragma unroll
    for (int i = 0; i < 16; ++i) o[i] = 0.f;
#pragma unroll
    for (int cc = 0; cc < 8; ++cc) {
        if (cc < nch) {
            const ushort* Op = &Opart[(size_t)(sbase + cc) * 16384 + row * 128 + h0];
            for (int x = 0; x < 2; ++x) {
                bf16x8 v = *(const bf16x8*)&Op[x * 8];
                for (int i2 = 0; i2 < 8; ++i2)
                    o[x * 8 + i2] += bf2f((ushort)v[i2]) * wgt[cc];
            }
        }
    }
    float inv = 1.0f / ltot;
    float* dst = &out[((size_t)(b * T) + j * 128 + row) * Hd + h0];
    for (int i = 0; i < 16; ++i) dst[i] = o[i] * inv;
}

// ---------------------------------------------------------------------------
extern "C" void kernel_launch(void* const* d_in, const int* in_sizes, int n_in,
                              void* d_out, int out_size, void* d_ws, size_t ws_size,
                              hipStream_t stream) {
    const float* x  = (const float*)d_in[0];
    const float* Wq = (const float*)d_in[1];
    const float* Wk = (const float*)d_in[2];
    const float* Wv = (const float*)d_in[3];
    float* out = (float*)d_out;

    // ws (~49.4 MB). Region A time-shared: Xb+Wb live until qkv_gemm ends;
    // Opart/mpart/lpart (written later by attn_partial) alias it.
    // Opart 576 slots * 32KB = 18.9 MB (fits under Xb's 33.55 MB).
    char* w = (char*)d_ws;
    ushort* Xb = (ushort*)w;                                   // 33.55 MB
    ushort* Wb = (ushort*)(w + (size_t)33554432);              // 0.79 MB
    ushort* Opart = (ushort*)w;                                // 576*32KB = 18.9 MB
    float* mpart = (float*)(w + (size_t)35651584);             // 0.29 MB used
    float* lpart = (float*)(w + (size_t)35651584 + 557056);    // 0.29 MB used
    w += (size_t)35651584 + 2 * 557056;
    ushort* Qb  = (ushort*)w;  w += (size_t)NB * T * Hd * 2;   // 4.19 MB
    ushort* Kb  = (ushort*)w;  w += (size_t)NB * T * Hd * 2;
    ushort* Vtb = (ushort*)w;  w += (size_t)NB * T * Hd * 2;

    convert_xw<<<8384, 256, 0, stream>>>(x, Wq, Wk, Wv, Xb, Wb);
    qkv_gemm<<<dim3(128, 6), 256, 0, stream>>>(Xb, Wb, Qb, Kb, Vtb);
    attn_partial<<<576, 256, 0, stream>>>(Qb, Kb, Vtb, Opart, mpart, lpart);
    attn_combine<<<dim3(16, 8, 4), 256, 0, stream>>>(Opart, mpart, lpart, out);
}

// Round 4
// 163.251 us; speedup vs baseline: 1.2768x; 1.2768x over previous
//
#include <hip/hip_runtime.h>
#include <hip/hip_bf16.h>

constexpr int NB = 8;      // batch
constexpr int T  = 2048;   // seq
constexpr int C  = 1024;   // embed
constexpr int Hd = 128;    // head size

typedef short bf16x8 __attribute__((ext_vector_type(8)));
typedef float floatx4 __attribute__((ext_vector_type(4)));

__device__ __forceinline__ ushort f2bf(float x) {
    return __builtin_bit_cast(ushort, __float2bfloat16(x));
}
__device__ __forceinline__ float bf2f(ushort u) {
    unsigned int x = ((unsigned int)u) << 16;
    return __builtin_bit_cast(float, x);
}
__device__ __forceinline__ void async16(ushort* lds, const ushort* g) {
    __builtin_amdgcn_global_load_lds(
        (const __attribute__((address_space(1))) unsigned int*)g,
        (__attribute__((address_space(3))) unsigned int*)lds, 16, 0, 0);
}

// ---------------------------------------------------------------------------
// Kernel 1: fused fp32->bf16 convert for X and stacked W (Wq scaled). UNCHANGED.
// ---------------------------------------------------------------------------
__global__ __launch_bounds__(256) void convert_xw(
    const float* __restrict__ X, const float* __restrict__ Wq,
    const float* __restrict__ Wk, const float* __restrict__ Wv,
    ushort* __restrict__ Xb, ushort* __restrict__ Wb)
{
    int bid = blockIdx.x;
    if (bid < 8192) {
        size_t i = ((size_t)bid * 256 + threadIdx.x) * 8;
        float4 a = *(const float4*)&X[i];
        float4 b = *(const float4*)&X[i + 4];
        bf16x8 o;
        o[0] = (short)f2bf(a.x); o[1] = (short)f2bf(a.y);
        o[2] = (short)f2bf(a.z); o[3] = (short)f2bf(a.w);
        o[4] = (short)f2bf(b.x); o[5] = (short)f2bf(b.y);
        o[6] = (short)f2bf(b.z); o[7] = (short)f2bf(b.w);
        *(bf16x8*)&Xb[i] = o;
    } else {
        int g = (bid - 8192) * 256 + threadIdx.x;
        size_t base = (size_t)g * 8;
        int sel = (int)(base >> 17);
        const float* W = sel == 0 ? Wq : (sel == 1 ? Wk : Wv);
        float s = (sel == 0) ? 0.12751744f : 1.0f;     // log2e/sqrt(128) in Wq
        size_t off = base - (size_t)sel * 131072;
        float4 a = *(const float4*)&W[off];
        float4 b = *(const float4*)&W[off + 4];
        bf16x8 o;
        o[0] = (short)f2bf(a.x * s); o[1] = (short)f2bf(a.y * s);
        o[2] = (short)f2bf(a.z * s); o[3] = (short)f2bf(a.w * s);
        o[4] = (short)f2bf(b.x * s); o[5] = (short)f2bf(b.y * s);
        o[6] = (short)f2bf(b.z * s); o[7] = (short)f2bf(b.w * s);
        *(bf16x8*)&Wb[base] = o;
    }
}

// ---------------------------------------------------------------------------
// Kernel 2: QKV GEMM bf16, BM=128 BN=64, NOW BK=128 (was 64).
// LDS 48KB (Al 32KB + Bl 16KB): 3 blocks/CU retained (grid 768 = 3/CU, 3*48
// = 144KB <= 160KB). Halves the per-block barrier-drain count (8 k-iters vs
// 16), 2x MFMA per staging phase. Swizzle: LDS[r][g] = src[r][g^(r&7)], rows
// now 128 ushorts (16 groups); read side row&7 == colL&7 as before. Same
// bank-conflict structure as BK=64 (verified by address arithmetic).
// ---------------------------------------------------------------------------
__global__ __launch_bounds__(256) void qkv_gemm(
    const ushort* __restrict__ Xb, const ushort* __restrict__ Wb,
    ushort* __restrict__ Qo, ushort* __restrict__ Ko, ushort* __restrict__ Vt)
{
    __shared__ ushort SM[24576];          // 48KB: Al(16384) + Bl(8192); TL overlays
    ushort* Al = SM;                      // 128x128
    ushort* Bl = SM + 16384;              // 64x128
    const int m0 = blockIdx.x * 128;
    const int n0 = blockIdx.y * 64;       // row into stacked Wb [384][1024]
    const int tid = threadIdx.x, lane = tid & 63, wave = tid >> 6;
    const int quad = lane >> 4, colL = lane & 15;
    const int wm = (wave & 1) * 64, wn = (wave >> 1) * 32;
    const int lr4 = lane >> 4;            // row within 4-row staging chunk
    const int cg  = lane & 15;            // LDS 16B column group

    floatx4 acc[4][2] = {};

    for (int k0 = 0; k0 < C; k0 += 128) {
        // A: 128 rows x 128 cols = 32 chunks of 4 rows; wave w stages 8 chunks
        for (int t = 0; t < 8; ++t) {
            int q = wave * 8 + t;
            int row = q * 4 + lr4;
            async16(&Al[q * 512 + lane * 8],
                    &Xb[(size_t)(m0 + row) * C + k0 + ((cg ^ (row & 7)) * 8)]);
        }
        // B: 64 rows -> 16 chunks; wave w stages 4 chunks
        for (int t = 0; t < 4; ++t) {
            int q = wave * 4 + t;
            int row = q * 4 + lr4;
            async16(&Bl[q * 512 + lane * 8],
                    &Wb[(size_t)(n0 + row) * C + k0 + ((cg ^ (row & 7)) * 8)]);
        }
        __syncthreads();

        for (int kk = 0; kk < 4; ++kk) {
            bf16x8 af[4], bfr[2];
            for (int mt = 0; mt < 4; ++mt)
                af[mt] = *(const bf16x8*)
                    &Al[(wm + mt * 16 + colL) * 128 + (((kk * 4 + quad) ^ (colL & 7))) * 8];
            for (int nt = 0; nt < 2; ++nt)
                bfr[nt] = *(const bf16x8*)
                    &Bl[(wn + nt * 16 + colL) * 128 + (((kk * 4 + quad) ^ (colL & 7))) * 8];
            for (int mt = 0; mt < 4; ++mt)
                for (int nt = 0; nt < 2; ++nt)
                    acc[mt][nt] = __builtin_amdgcn_mfma_f32_16x16x32_bf16(
                        af[mt], bfr[nt], acc[mt][nt], 0, 0, 0);
        }
        __syncthreads();
    }

    const int sel = n0 >> 7;              // 0,0,1,1,2,2
    const int h0 = n0 & 127;              // 0 or 64
    if (sel < 2) {
        ushort* dst = sel == 0 ? Qo : Ko;
        for (int mt = 0; mt < 4; ++mt)
            for (int nt = 0; nt < 2; ++nt)
                for (int r = 0; r < 4; ++r) {
                    int row = m0 + wm + mt * 16 + quad * 4 + r;
                    int h = h0 + wn + nt * 16 + colL;
                    dst[(size_t)row * Hd + h] = f2bf(acc[mt][nt][r]);
                }
    } else {
        // V: transpose 128t x 64h tile through LDS scratch TL[128][66]
        ushort* TL = SM;                  // 8448 ushorts, overlays Al/Bl
        for (int mt = 0; mt < 4; ++mt)
            for (int nt = 0; nt < 2; ++nt)
                for (int r = 0; r < 4; ++r)
                    TL[(wm + mt * 16 + quad * 4 + r) * 66 + wn + nt * 16 + colL] =
                        f2bf(acc[mt][nt][r]);
        __syncthreads();
        const int b = m0 >> 11, tb = m0 & 2047;
        const int h = tid & 63, tq = tid >> 6;     // thread: h col, 32-t strip
        for (int st = 0; st < 4; ++st) {
            int t0 = tq * 32 + st * 8;
            bf16x8 o;
            for (int jx = 0; jx < 8; ++jx)
                o[jx] = (short)TL[(t0 + jx) * 66 + h];
            *(bf16x8*)&Vt[((size_t)b * Hd + h0 + h) * T + tb + t0] = o;
        }
    }
}

// ---------------------------------------------------------------------------
// Kernel 3: split-K causal flash attention — EXACT R0 revert (known-good,
// spill-free). Block = (b, qblock j of 128 rows, kchunk c of 128 keys),
// c <= j. ONE staging iteration -> no online rescale. LDS 64KB, XOR-swizzled.
// R1-R3 lesson: any structure where score-state and O-state coexist beyond
// ~128 regs spills on gfx950 (arch/acc split); here accS retires into P(LDS)
// before Oacc is born.
// ---------------------------------------------------------------------------
__global__ __launch_bounds__(256, 2) void attn_partial(
    const ushort* __restrict__ Q, const ushort* __restrict__ Kg,
    const ushort* __restrict__ Vt, ushort* __restrict__ Opart,
    float* __restrict__ mpart, float* __restrict__ lpart)
{
    __shared__ ushort Kl[128 * 128];   // 32KB [key][h] swizzled; P aliases later
    __shared__ ushort Vl[128 * 128];   // 32KB [h][key] swizzled

    const int tid = threadIdx.x, lane = tid & 63, wave = tid >> 6;
    const int quad = lane >> 4, colL = lane & 15;

    int id = blockIdx.x;               // 0..1087, heavy-first decode
    int b = id / 136;
    int rem = id - b * 136;
    int j = 15;
    while (rem >= j + 1) { rem -= (j + 1); --j; }
    int c = rem;
    const int q0 = j * 128;
    const int k0 = c * 128;
    const bool diag = (c == j);

    {
        int r = tid >> 4, p = tid & 15;
        for (int t = 0; t < 8; ++t) {
            int row = t * 16 + r;
            async16(&Kl[t * 2048 + tid * 8],
                    &Kg[((size_t)b * T + k0 + row) * Hd + ((p ^ (row & 15)) * 8)]);
        }
        for (int t = 0; t < 8; ++t) {
            int hrow = t * 16 + r;
            async16(&Vl[t * 2048 + tid * 8],
                    &Vt[((size_t)b * Hd + hrow) * T + k0 + ((p ^ (hrow & 15)) * 8)]);
        }
    }

    bf16x8 qa[2][4];
    for (int mi = 0; mi < 2; ++mi) {
        const ushort* qp =
            &Q[((size_t)b * T + q0 + wave * 32 + mi * 16 + colL) * Hd + quad * 8];
        for (int ks = 0; ks < 4; ++ks)
            qa[mi][ks] = *(const bf16x8*)&qp[ks * 32];
    }

    __syncthreads();

    floatx4 accS[2][8] = {};
    for (int ks = 0; ks < 4; ++ks)
        for (int nt = 0; nt < 8; ++nt) {
            int krow = nt * 16 + colL;
            bf16x8 kb = *(const bf16x8*)&Kl[krow * 128 + (((ks * 4 + quad) ^ colL) * 8)];
            accS[0][nt] = __builtin_amdgcn_mfma_f32_16x16x32_bf16(qa[0][ks], kb, accS[0][nt], 0, 0, 0);
            accS[1][nt] = __builtin_amdgcn_mfma_f32_16x16x32_bf16(qa[1][ks], kb, accS[1][nt], 0, 0, 0);
        }

    if (diag) {
        for (int mi = 0; mi < 2; ++mi)
            for (int nt = 0; nt < 8; ++nt)
                for (int rr = 0; rr < 4; ++rr) {
                    int lrow = wave * 32 + mi * 16 + quad * 4 + rr;
                    int lcol = nt * 16 + colL;
                    if (lcol > lrow) accS[mi][nt][rr] = -__builtin_inff();
                }
    }
    __syncthreads();   // Kl reads complete; P may alias

    ushort* Pw = &Kl[wave * 4096];     // [32 rows][128 keys], col^((row&7)<<4)
    float m_r[2][4], l_r[2][4];
    for (int mi = 0; mi < 2; ++mi)
        for (int rr = 0; rr < 4; ++rr) {
            float mx = accS[mi][0][rr];
            for (int nt = 1; nt < 8; ++nt) mx = fmaxf(mx, accS[mi][nt][rr]);
            for (int off = 1; off < 16; off <<= 1)
                mx = fmaxf(mx, __shfl_xor(mx, off, 64));
            m_r[mi][rr] = mx;
            l_r[mi][rr] = 0.f;
        }
    for (int mi = 0; mi < 2; ++mi) {
        for (int nt = 0; nt < 8; ++nt)
            for (int rr = 0; rr < 4; ++rr) {
                float p = __builtin_amdgcn_exp2f(accS[mi][nt][rr] - m_r[mi][rr]);
                l_r[mi][rr] += p;
                int prow = mi * 16 + quad * 4 + rr;
                Pw[prow * 128 + ((nt * 16 + colL) ^ ((prow & 7) << 4))] = f2bf(p);
            }
        for (int rr = 0; rr < 4; ++rr) {
            float s = l_r[mi][rr];
            for (int off = 1; off < 16; off <<= 1)
                s += __shfl_xor(s, off, 64);
            l_r[mi][rr] = s;
        }
    }

    bf16x8 pa[2][4];
    for (int mi = 0; mi < 2; ++mi) {
        int prow = mi * 16 + colL;
        int sw = (prow & 7) << 4;
        for (int ks = 0; ks < 4; ++ks)
            pa[mi][ks] = *(const bf16x8*)&Pw[prow * 128 + ((ks * 32 + quad * 8) ^ sw)];
    }

    floatx4 Oacc[2][8] = {};
    for (int ks = 0; ks < 4; ++ks)
        for (int th = 0; th < 8; ++th) {
            int hrow = th * 16 + colL;
            bf16x8 vb = *(const bf16x8*)&Vl[hrow * 128 + (((ks * 4 + quad) ^ colL) * 8)];
            Oacc[0][th] = __builtin_amdgcn_mfma_f32_16x16x32_bf16(pa[0][ks], vb, Oacc[0][th], 0, 0, 0);
            Oacc[1][th] = __builtin_amdgcn_mfma_f32_16x16x32_bf16(pa[1][ks], vb, Oacc[1][th], 0, 0, 0);
        }

    const int slot = b * 136 + (j * (j + 1)) / 2 + c;
    ushort* Op = &Opart[(size_t)slot * 16384];
    for (int mi = 0; mi < 2; ++mi)
        for (int th = 0; th < 8; ++th)
            for (int rr = 0; rr < 4; ++rr) {
                int row = wave * 32 + mi * 16 + quad * 4 + rr;
                Op[row * 128 + th * 16 + colL] = f2bf(Oacc[mi][th][rr]);
            }
    if (colL == 0)
        for (int mi = 0; mi < 2; ++mi)
            for (int rr = 0; rr < 4; ++rr) {
                int row = wave * 32 + mi * 16 + quad * 4 + rr;
                mpart[(size_t)slot * 128 + row] = m_r[mi][rr];
                lpart[(size_t)slot * 128 + row] = l_r[mi][rr];
            }
}

// ---------------------------------------------------------------------------
// Kernel 4: merge partials, write fp32 out — EXACT R0 revert.
// Grid (16 j, 8 b, 4 rowquarter) = 512 blocks. Thread owns (row, 16-h chunk).
// ---------------------------------------------------------------------------
__global__ __launch_bounds__(256) void attn_combine(
    const ushort* __restrict__ Opart, const float* __restrict__ mpart,
    const float* __restrict__ lpart, float* __restrict__ out)
{
    const int j = blockIdx.x, b = blockIdx.y;
    const int nch = j + 1;
    const int sbase = b * 136 + (j * (j + 1)) / 2;
    const int t = threadIdx.x;
    const int row = blockIdx.z * 32 + (t >> 3);
    const int h0 = (t & 7) * 16;

    float M = -__builtin_inff();
    for (int c = 0; c < nch; ++c)
        M = fmaxf(M, mpart[(size_t)(sbase + c) * 128 + row]);
    float ltot = 0.f;
    for (int c = 0; c < nch; ++c)
        ltot += lpart[(size_t)(sbase + c) * 128 + row] *
                __builtin_amdgcn_exp2f(mpart[(size_t)(sbase + c) * 128 + row] - M);

    float o[16];
    for (int i = 0; i < 16; ++i) o[i] = 0.f;
    for (int c = 0; c < nch; ++c) {
        float wgt = __builtin_amdgcn_exp2f(mpart[(size_t)(sbase + c) * 128 + row] - M);
        const ushort* Op = &Opart[(size_t)(sbase + c) * 16384 + row * 128 + h0];
        for (int x = 0; x < 2; ++x) {
            bf16x8 v = *(const bf16x8*)&Op[x * 8];
            for (int i2 = 0; i2 < 8; ++i2)
                o[x * 8 + i2] += bf2f((ushort)v[i2]) * wgt;
        }
    }
    float inv = 1.0f / ltot;
    float* dst = &out[((size_t)(b * T) + j * 128 + row) * Hd + h0];
    for (int i = 0; i < 16; ++i) dst[i] = o[i] * inv;
}

// ---------------------------------------------------------------------------
extern "C" void kernel_launch(void* const* d_in, const int* in_sizes, int n_in,
                              void* d_out, int out_size, void* d_ws, size_t ws_size,
                              hipStream_t stream) {
    const float* x  = (const float*)d_in[0];
    const float* Wq = (const float*)d_in[1];
    const float* Wk = (const float*)d_in[2];
    const float* Wv = (const float*)d_in[3];
    float* out = (float*)d_out;

    // ws (~49.4 MB). Region A time-shared: Xb+Wb live until qkv_gemm ends;
    // Opart/mpart/lpart (written later by attn_partial) alias it.
    char* w = (char*)d_ws;
    ushort* Xb = (ushort*)w;                                   // 33.55 MB
    ushort* Wb = (ushort*)(w + (size_t)33554432);              // 0.79 MB
    ushort* Opart = (ushort*)w;                                // 1088*32KB = 35.65 MB
    float* mpart = (float*)(w + (size_t)35651584);             // 0.56 MB
    float* lpart = (float*)(w + (size_t)35651584 + 557056);    // 0.56 MB
    w += (size_t)35651584 + 2 * 557056;
    ushort* Qb  = (ushort*)w;  w += (size_t)NB * T * Hd * 2;   // 4.19 MB
    ushort* Kb  = (ushort*)w;  w += (size_t)NB * T * Hd * 2;
    ushort* Vtb = (ushort*)w;  w += (size_t)NB * T * Hd * 2;

    convert_xw<<<8384, 256, 0, stream>>>(x, Wq, Wk, Wv, Xb, Wb);
    qkv_gemm<<<dim3(128, 6), 256, 0, stream>>>(Xb, Wb, Qb, Kb, Vtb);
    attn_partial<<<1088, 256, 0, stream>>>(Qb, Kb, Vtb, Opart, mpart, lpart);
    attn_combine<<<dim3(16, 8, 4), 256, 0, stream>>>(Opart, mpart, lpart, out);
}